// Round 2
// baseline (1484.811 us; speedup 1.0000x reference)
//
#include <hip/hip_runtime.h>
#include <stdint.h>

typedef uint16_t u16;
typedef __attribute__((ext_vector_type(8))) short s16x8;
typedef __attribute__((ext_vector_type(4))) float f32x4;

typedef const __attribute__((address_space(1))) void* gptr_t;
typedef __attribute__((address_space(3))) void* lptr_t;

__device__ __forceinline__ float bf2f(u16 u) { return __uint_as_float(((unsigned)u) << 16); }
__device__ __forceinline__ u16 f2bf(float f) {
    unsigned u = __float_as_uint(f);
    u += 0x7fffu + ((u >> 16) & 1u);   // RNE (finite values only in this net)
    return (u16)(u >> 16);
}
__device__ __forceinline__ void gld_lds16(const void* g, void* l) {
    __builtin_amdgcn_global_load_lds((gptr_t)g, (lptr_t)l, 16, 0, 0);
}

// ---------------------------------------------------------------------------
// f32 -> bf16 conversion, 8 elems/thread, n % 2048 == 0
// ---------------------------------------------------------------------------
__global__ __launch_bounds__(256) void cvt_f32_bf16(const float* __restrict__ src,
                                                    u16* __restrict__ dst, long n)
{
    const long i = ((long)blockIdx.x * 256 + threadIdx.x) * 8;
    if (i >= n) return;
    float4 a = *(const float4*)(src + i);
    float4 b = *(const float4*)(src + i + 4);
    u16 o8[8] = { f2bf(a.x), f2bf(a.y), f2bf(a.z), f2bf(a.w),
                  f2bf(b.x), f2bf(b.y), f2bf(b.z), f2bf(b.w) };
    *(uint4*)(dst + i) = *(const uint4*)o8;
}

// ---------------------------------------------------------------------------
// gemm256: C[M,N] = A[M,K] @ B[N,K]^T  (bf16 in, bf16 out), 256x256 tile,
// BK=64, 8 waves (2M x 4N, each 128x64 out), double-buffered swizzled LDS,
// 4 phases/K-tile with spread prefetch issue (T2+T3-lite+T5).
// Requires M%256==0, N%256==0, K%64==0, grid.x = (M/256)*(N/256), %8==0.
// ---------------------------------------------------------------------------
__global__ __launch_bounds__(512, 2) void gemm256(
        const u16* __restrict__ A, const u16* __restrict__ B,
        u16* __restrict__ Cb, int M, int N, int K, int gx)
{
    __shared__ __align__(16) u16 As[2][256 * 64];
    __shared__ __align__(16) u16 Bs[2][256 * 64];

    const int tid  = threadIdx.x;
    const int wave = tid >> 6, lane = tid & 63;
    const int quad = lane >> 4, l16 = lane & 15;
    const int wmi = wave >> 2, wni = wave & 3;

    // XCD-aware swizzle (grid.x % 8 == 0 at both call sites)
    const int cpx = gridDim.x >> 3;
    const int wg  = ((int)blockIdx.x & 7) * cpx + ((int)blockIdx.x >> 3);
    const long m0 = (long)(wg / gx) * 256;
    const long n0 = (long)(wg % gx) * 256;

    f32x4 acc[8][4] = {};

    // staging: 2048 chunks of 16B per 256x64 tile; thread handles chunks
    // c=i*512+tid, i=0..3. row=c>>3, col8=(c&7)*8, source col pre-swizzled.
    const u16* Ag = A + m0 * (long)K;
    const u16* Bg = B + n0 * (long)K;
    long soff[4];
    int  lbase[4];
#pragma unroll
    for (int i = 0; i < 4; i++) {
        const int c = i * 512 + tid;
        const int row = c >> 3, col8 = (c & 7) * 8;
        soff[i]  = (long)row * K + (col8 ^ ((row & 7) << 3));
        lbase[i] = (i * 512 + wave * 64) * 8;   // wave-uniform LDS base (elems)
    }

    // prologue: stage tile 0 into buffer 0
#pragma unroll
    for (int i = 0; i < 4; i++) {
        gld_lds16(Ag + soff[i], &As[0][lbase[i]]);
        gld_lds16(Bg + soff[i], &Bs[0][lbase[i]]);
    }
    __syncthreads();   // vmcnt(0) drain -> tile 0 visible

    const int swz   = (l16 & 7) << 3;
    const int arow0 = wmi * 128 + l16;
    const int brow0 = wni * 64 + l16;

    int db = 0;
    for (int k0 = 0; k0 < K; k0 += 64) {
        const int  kn = k0 + 64;
        const bool pf = kn < K;
        s16x8 bfrag[4][2];
#pragma unroll
        for (int p = 0; p < 4; p++) {
            // issue 1/4 of next tile's staging (lands in db^1 asynchronously)
            if (pf) {
                gld_lds16(Ag + soff[p] + kn, &As[db ^ 1][lbase[p]]);
                gld_lds16(Bg + soff[p] + kn, &Bs[db ^ 1][lbase[p]]);
            }
            if (p == 0) {
#pragma unroll
                for (int nt = 0; nt < 4; nt++)
#pragma unroll
                    for (int kk = 0; kk < 2; kk++)
                        bfrag[nt][kk] = *(const s16x8*)&Bs[db][(brow0 + nt * 16) * 64
                                            + ((kk * 32 + quad * 8) ^ swz)];
            }
            s16x8 af[2][2];
#pragma unroll
            for (int mtl = 0; mtl < 2; mtl++)
#pragma unroll
                for (int kk = 0; kk < 2; kk++)
                    af[mtl][kk] = *(const s16x8*)&As[db][(arow0 + (2 * p + mtl) * 16) * 64
                                        + ((kk * 32 + quad * 8) ^ swz)];
            __builtin_amdgcn_s_setprio(1);
#pragma unroll
            for (int mtl = 0; mtl < 2; mtl++)
#pragma unroll
                for (int nt = 0; nt < 4; nt++)
#pragma unroll
                    for (int kk = 0; kk < 2; kk++)
                        acc[2 * p + mtl][nt] = __builtin_amdgcn_mfma_f32_16x16x32_bf16(
                            af[mtl][kk], bfrag[nt][kk], acc[2 * p + mtl][nt], 0, 0, 0);
            __builtin_amdgcn_s_setprio(0);
        }
        __syncthreads();   // vmcnt(0)+lgkmcnt(0) drain; issued >=1 tile of MFMA ago
        db ^= 1;
    }

    // epilogue: C/D layout col=l16, row=quad*4+r
#pragma unroll
    for (int mt = 0; mt < 8; mt++)
#pragma unroll
        for (int nt = 0; nt < 4; nt++) {
            const long col = n0 + wni * 64 + nt * 16 + l16;
#pragma unroll
            for (int r = 0; r < 4; r++) {
                const long row = m0 + wmi * 128 + mt * 16 + quad * 4 + r;
                Cb[row * (long)N + col] = f2bf(acc[mt][nt][r]);
            }
        }
}

// ---------------------------------------------------------------------------
// GEMM:  C[M,N] = A[M,K] @ B[N,K]^T   (A,B bf16, A row stride lda)
// m97 structure: 128x128 tile, BK=32, 4 waves (2x2 of 64x64), 16x16x32 MFMA.
// ep=0: Cb[idx] = bf16(acc)        ep=1: Cf[idx] = acc + Rf[idx]   (f32)
// ---------------------------------------------------------------------------
__global__ __launch_bounds__(256) void gemm_bt(
        const u16* __restrict__ A, const u16* __restrict__ B,
        u16* __restrict__ Cb, float* __restrict__ Cf, const float* __restrict__ Rf,
        int M, int N, int K, int lda, int ep)
{
    __shared__ __align__(16) u16 As[128 * 32];
    __shared__ __align__(16) u16 Bs[128 * 32];

    const int tid  = threadIdx.x;
    const int wave = tid >> 6, lane = tid & 63;
    const int quad = lane >> 4, l16 = lane & 15;
    const long m0 = (long)blockIdx.y * 128, n0 = (long)blockIdx.x * 128;
    const int wm = (wave >> 1) * 64, wn = (wave & 1) * 64;

    f32x4 acc[4][4] = {};

    const int c0 = tid, c1 = tid + 256;
    const u16* Ag = A + m0 * (long)lda;
    const u16* Bg = B + n0 * (long)K;
    const long aA0 = (long)(c0 >> 2) * lda + (c0 & 3) * 8;
    const long aA1 = (long)(c1 >> 2) * lda + (c1 & 3) * 8;
    const long aB0 = (long)(c0 >> 2) * K + (c0 & 3) * 8;
    const long aB1 = (long)(c1 >> 2) * K + (c1 & 3) * 8;
    const int lb0 = (wave * 64) * 8;
    const int lb1 = (256 + wave * 64) * 8;

    for (int k0 = 0; k0 < K; k0 += 32) {
        __syncthreads();
        gld_lds16(Ag + aA0 + k0, &As[lb0]);
        gld_lds16(Ag + aA1 + k0, &As[lb1]);
        gld_lds16(Bg + aB0 + k0, &Bs[lb0]);
        gld_lds16(Bg + aB1 + k0, &Bs[lb1]);
        __syncthreads();

        s16x8 af[4], bfr[4];
#pragma unroll
        for (int t = 0; t < 4; t++) {
            af[t]  = *(const s16x8*)&As[(wm + t * 16 + l16) * 32 + quad * 8];
            bfr[t] = *(const s16x8*)&Bs[(wn + t * 16 + l16) * 32 + quad * 8];
        }
#pragma unroll
        for (int mt = 0; mt < 4; mt++)
#pragma unroll
            for (int nt = 0; nt < 4; nt++)
                acc[mt][nt] = __builtin_amdgcn_mfma_f32_16x16x32_bf16(
                    af[mt], bfr[nt], acc[mt][nt], 0, 0, 0);
    }

#pragma unroll
    for (int mt = 0; mt < 4; mt++)
#pragma unroll
        for (int nt = 0; nt < 4; nt++) {
            const long col = n0 + wn + nt * 16 + l16;
#pragma unroll
            for (int r = 0; r < 4; r++) {
                const long row = m0 + wm + mt * 16 + quad * 4 + r;
                const long idx = row * N + col;
                const float v = acc[mt][nt][r];
                if (ep == 0) Cb[idx] = f2bf(v);
                else         Cf[idx] = v + Rf[idx];
            }
        }
}

// ---------------------------------------------------------------------------
// Flash attention, Br=64 (16 q-rows/wave), Bc=64, head_dim=128, S=2048.
// q/k/v (bf16) layout: [B,S,NH,HD] with row stride ld. bias/mask f32.
// LDS tiles XOR-swizzled (see R1). Output O row stride 2048.
// ---------------------------------------------------------------------------
__global__ __launch_bounds__(256) void flash_attn(
        const u16* __restrict__ Q, const u16* __restrict__ Kp,
        const u16* __restrict__ V, int ld, const float* __restrict__ bias,
        const float* __restrict__ mask, u16* __restrict__ O)
{
    const int tid  = threadIdx.x;
    const int wave = tid >> 6, lane = tid & 63;
    const int quad = lane >> 4, l16 = lane & 15;
    const int q0 = blockIdx.x * 64, h = blockIdx.y, b = blockIdx.z;

    __shared__ __align__(16) u16 Ks[64 * 128];      // [k][d] row-major, swizzled
    __shared__ __align__(16) u16 Vt[128 * 64];      // [d][k] transposed, swizzled
    __shared__ __align__(16) u16 Ps[4][16 * 64];    // per-wave P, swizzled

    const long baseI = (long)b * 2048 * ld + (long)h * 128;
    const long baseO = (long)b * 2048 * 2048 + (long)h * 128;

    s16x8 qf[4];
    {
        const u16* qp = Q + baseI + (long)(q0 + wave * 16 + l16) * ld;
#pragma unroll
        for (int kk = 0; kk < 4; kk++)
            qf[kk] = *(const s16x8*)(qp + kk * 32 + quad * 8);
    }

    f32x4 oacc[8] = {};
    float m_i[4] = { -1e30f, -1e30f, -1e30f, -1e30f };
    float l_i[4] = { 0.f, 0.f, 0.f, 0.f };
    const float scale = 0.08838834764831845f;  // 1/sqrt(128)
    const int kswz = (l16 & 7) << 3;

    for (int k0 = 0; k0 < 2048; k0 += 64) {
        __syncthreads();
#pragma unroll
        for (int it = 0; it < 4; it++) {
            const int c = it * 256 + tid;
            const int row = c >> 4, col8 = (c & 15) * 8;
            const int src = col8 ^ ((row & 7) << 3);
            gld_lds16(Kp + baseI + (long)(k0 + row) * ld + src,
                      &Ks[(it * 256 + wave * 64) * 8]);
        }
#pragma unroll
        for (int it = 0; it < 4; it++) {
            const int c = it * 256 + tid;
            const int row = c >> 4, col8 = (c & 15) * 8;
            uint4 raw = *(const uint4*)(V + baseI + (long)(k0 + row) * ld + col8);
            const u16* e = (const u16*)&raw;
#pragma unroll
            for (int j = 0; j < 8; j++) {
                const int d = col8 + j;
                const int swzv = ((d & 7) ^ ((d >> 3) & 7)) << 3;
                Vt[d * 64 + (row ^ swzv)] = e[j];
            }
        }
        __syncthreads();

        float sv[4][4];
#pragma unroll
        for (int nt = 0; nt < 4; nt++) {
            f32x4 sa = { 0.f, 0.f, 0.f, 0.f };
#pragma unroll
            for (int kk = 0; kk < 4; kk++) {
                s16x8 kf = *(const s16x8*)&Ks[(nt * 16 + l16) * 128
                                              + ((kk * 32 + quad * 8) ^ kswz)];
                sa = __builtin_amdgcn_mfma_f32_16x16x32_bf16(qf[kk], kf, sa, 0, 0, 0);
            }
            const int kcol = k0 + nt * 16 + l16;
#pragma unroll
            for (int r = 0; r < 4; r++) {
                const int qrow = q0 + wave * 16 + quad * 4 + r;
                float val = sa[r] * scale;
                val += bias[((long)h * 2048 + qrow) * 2048 + kcol];
                val += mask[(long)qrow * 2048 + kcol];
                sv[nt][r] = val;
            }
        }

        float alpha[4];
#pragma unroll
        for (int r = 0; r < 4; r++) {
            float mx = fmaxf(fmaxf(sv[0][r], sv[1][r]), fmaxf(sv[2][r], sv[3][r]));
#pragma unroll
            for (int off = 1; off < 16; off <<= 1) mx = fmaxf(mx, __shfl_xor(mx, off));
            const float mnew = fmaxf(m_i[r], mx);
            alpha[r] = __expf(m_i[r] - mnew);
            m_i[r] = mnew;
            float rs = 0.f;
#pragma unroll
            for (int nt = 0; nt < 4; nt++) {
                const float pv = __expf(sv[nt][r] - mnew);
                sv[nt][r] = pv;
                rs += pv;
            }
#pragma unroll
            for (int off = 1; off < 16; off <<= 1) rs += __shfl_xor(rs, off);
            l_i[r] = l_i[r] * alpha[r] + rs;
        }

#pragma unroll
        for (int nt = 0; nt < 4; nt++)
#pragma unroll
            for (int r = 0; r < 4; r++) {
                const int prow = quad * 4 + r;
                Ps[wave][prow * 64 + ((nt * 16 + l16) ^ ((prow & 7) << 3))]
                    = f2bf(sv[nt][r]);
            }

#pragma unroll
        for (int dt = 0; dt < 8; dt++)
#pragma unroll
            for (int r = 0; r < 4; r++)
                oacc[dt][r] *= alpha[r];

#pragma unroll
        for (int kk2 = 0; kk2 < 2; kk2++) {
            s16x8 pf = *(const s16x8*)&Ps[wave][l16 * 64
                                               + ((kk2 * 32 + quad * 8) ^ kswz)];
#pragma unroll
            for (int dt = 0; dt < 8; dt++) {
                const int d = dt * 16 + l16;
                const int vswz = ((d & 7) ^ ((d >> 3) & 7)) << 3;
                s16x8 vf = *(const s16x8*)&Vt[d * 64
                                              + ((kk2 * 32 + quad * 8) ^ vswz)];
                oacc[dt] = __builtin_amdgcn_mfma_f32_16x16x32_bf16(pf, vf, oacc[dt], 0, 0, 0);
            }
        }
    }

#pragma unroll
    for (int dt = 0; dt < 8; dt++)
#pragma unroll
        for (int r = 0; r < 4; r++) {
            const int qrow = q0 + wave * 16 + quad * 4 + r;
            O[baseO + (long)qrow * 2048 + dt * 16 + l16] = f2bf(oacc[dt][r] / l_i[r]);
        }
}

// ---------------------------------------------------------------------------
// RMSNorm: f32 in (row of 2048), f32 weight, bf16 out. One block per row.
// ---------------------------------------------------------------------------
__global__ __launch_bounds__(256) void rmsnorm_f32(
        const float* __restrict__ x, const float* __restrict__ w,
        u16* __restrict__ out)
{
    const int row = blockIdx.x, tid = threadIdx.x;
    const float* xr = x + (long)row * 2048;
    float4 f0 = *(const float4*)(xr + tid * 8);
    float4 f1 = *(const float4*)(xr + tid * 8 + 4);
    float v[8] = { f0.x, f0.y, f0.z, f0.w, f1.x, f1.y, f1.z, f1.w };
    float ss = 0.f;
#pragma unroll
    for (int j = 0; j < 8; j++) ss += v[j] * v[j];
#pragma unroll
    for (int off = 32; off > 0; off >>= 1) ss += __shfl_xor(ss, off);
    __shared__ float red[4];
    if ((tid & 63) == 0) red[tid >> 6] = ss;
    __syncthreads();
    const float tot = red[0] + red[1] + red[2] + red[3];
    const float sc = rsqrtf(tot * (1.0f / 2048.0f) + 1e-5f);
    float4 w0 = *(const float4*)(w + tid * 8);
    float4 w1v = *(const float4*)(w + tid * 8 + 4);
    const float wv[8] = { w0.x, w0.y, w0.z, w0.w, w1v.x, w1v.y, w1v.z, w1v.w };
    u16 o8[8];
#pragma unroll
    for (int j = 0; j < 8; j++) o8[j] = f2bf(v[j] * sc * wv[j]);
    *(uint4*)(out + (long)row * 2048 + tid * 8) = *(const uint4*)o8;
}

// ---------------------------------------------------------------------------
// g = silu(a)*b on the fused [4096, 11264] buffer: a = cols 0..5631,
// b = cols 5632..11263, g written in place over a. One block per row.
// ---------------------------------------------------------------------------
__global__ __launch_bounds__(704) void silu_mul_rows(u16* __restrict__ s13)
{
    const long rb = (long)blockIdx.x * 11264;
    const int col8 = threadIdx.x * 8;
    uint4 ra = *(const uint4*)(s13 + rb + col8);
    uint4 rbv = *(const uint4*)(s13 + rb + 5632 + col8);
    const u16* ea = (const u16*)&ra;
    const u16* eb = (const u16*)&rbv;
    u16 o8[8];
#pragma unroll
    for (int j = 0; j < 8; j++) {
        const float fa = bf2f(ea[j]);
        const float fb = bf2f(eb[j]);
        const float s = fa / (1.f + __expf(-fa));
        o8[j] = f2bf(s * fb);
    }
    *(uint4*)(s13 + rb + col8) = *(const uint4*)o8;
}

// ---------------------------------------------------------------------------
extern "C" void kernel_launch(void* const* d_in, const int* in_sizes, int n_in,
                              void* d_out, int out_size, void* d_ws, size_t ws_size,
                              hipStream_t stream)
{
    const float* x    = (const float*)d_in[0];
    const float* mask = (const float*)d_in[1];
    const float* bias = (const float*)d_in[2];
    const float* wq   = (const float*)d_in[3];
    const float* wk   = (const float*)d_in[4];
    const float* wv   = (const float*)d_in[5];
    const float* wo   = (const float*)d_in[6];
    const float* w1   = (const float*)d_in[7];
    const float* w2   = (const float*)d_in[8];
    const float* w3   = (const float*)d_in[9];
    const float* anw  = (const float*)d_in[10];
    const float* fnw  = (const float*)d_in[11];
    float* out = (float*)d_out;       // also doubles as h1 (f32 residual buffer)

    const long SZA = 2048L * 2048;    // attention weight elems
    const long SZF = 5632L * 2048;    // FFN weight elems

    char* p = (char*)d_ws;
    // wq,wk,wv contiguous -> fused [6144,2048] B; w1,w3 contiguous -> [11264,2048]
    u16* wqb = (u16*)p;  u16* wkb = wqb + SZA;  u16* wvb = wkb + SZA;
    u16* wob = wvb + SZA;
    u16* w1b = wob + SZA;  u16* w3b = w1b + SZF;  u16* w2b = w3b + SZF;
    p += (4 * SZA + 3 * SZF) * 2;
    const size_t SZ = (size_t)4096 * 2048 * 2;           // 16 MiB bf16 activation
    u16* h_buf  = (u16*)p;  p += SZ;                     // h, attn_out, f
    u16* qkv    = (u16*)p;  p += (size_t)4096 * 6144 * 2;   // fused q|k|v
    u16* s13    = (u16*)p;  p += (size_t)4096 * 11264 * 2;  // fused w1|w3 out, g
    // total ws used ~238 MB

    // weights f32 -> bf16
    cvt_f32_bf16<<<2048, 256, 0, stream>>>(wq, wqb, SZA);
    cvt_f32_bf16<<<2048, 256, 0, stream>>>(wk, wkb, SZA);
    cvt_f32_bf16<<<2048, 256, 0, stream>>>(wv, wvb, SZA);
    cvt_f32_bf16<<<2048, 256, 0, stream>>>(wo, wob, SZA);
    cvt_f32_bf16<<<5632, 256, 0, stream>>>(w1, w1b, SZF);
    cvt_f32_bf16<<<5632, 256, 0, stream>>>(w3, w3b, SZF);
    cvt_f32_bf16<<<5632, 256, 0, stream>>>(w2, w2b, SZF);

    rmsnorm_f32<<<4096, 256, 0, stream>>>(x, anw, h_buf);
    // fused QKV: [4096,6144] = h @ [wq;wk;wv]^T   grid 24*16=384 (%8==0)
    gemm256<<<384, 512, 0, stream>>>(h_buf, wqb, qkv, 4096, 6144, 2048, 24);
    flash_attn<<<dim3(32, 16, 2), 256, 0, stream>>>(qkv, qkv + 2048, qkv + 4096,
                                                    6144, bias, mask, h_buf);
    // h1 = x + attn_out @ wo^T   (f32, stored in d_out)
    gemm_bt<<<dim3(16, 32), 256, 0, stream>>>(h_buf, wob, nullptr, out, x,
                                              4096, 2048, 2048, 2048, 1);
    rmsnorm_f32<<<4096, 256, 0, stream>>>(out, fnw, h_buf);
    // fused FFN up: [4096,11264] = f @ [w1;w3]^T  grid 44*16=704 (%8==0)
    gemm256<<<704, 512, 0, stream>>>(h_buf, w1b, s13, 4096, 11264, 2048, 44);
    silu_mul_rows<<<4096, 704, 0, stream>>>(s13);
    // out = h1 + g @ w2^T   (g = s13 cols 0..5631, row stride 11264)
    gemm_bt<<<dim3(16, 32), 256, 0, stream>>>(s13, w2b, nullptr, out, out,
                                              4096, 2048, 5632, 11264, 1);
}

// Round 3
// 1437.138 us; speedup vs baseline: 1.0332x; 1.0332x over previous
//
#include <hip/hip_runtime.h>
#include <stdint.h>

typedef uint16_t u16;
typedef __attribute__((ext_vector_type(8))) short s16x8;
typedef __attribute__((ext_vector_type(4))) float f32x4;

typedef const __attribute__((address_space(1))) void* gptr_t;
typedef __attribute__((address_space(3))) void* lptr_t;

__device__ __forceinline__ float bf2f(u16 u) { return __uint_as_float(((unsigned)u) << 16); }
__device__ __forceinline__ u16 f2bf(float f) {
    unsigned u = __float_as_uint(f);
    u += 0x7fffu + ((u >> 16) & 1u);   // RNE (finite values only in this net)
    return (u16)(u >> 16);
}
__device__ __forceinline__ void gld_lds16(const void* g, void* l) {
    __builtin_amdgcn_global_load_lds((gptr_t)g, (lptr_t)l, 16, 0, 0);
}

// ---------------------------------------------------------------------------
// f32 -> bf16 conversion, 8 elems/thread, n % 2048 == 0
// ---------------------------------------------------------------------------
__global__ __launch_bounds__(256) void cvt_f32_bf16(const float* __restrict__ src,
                                                    u16* __restrict__ dst, long n)
{
    const long i = ((long)blockIdx.x * 256 + threadIdx.x) * 8;
    if (i >= n) return;
    float4 a = *(const float4*)(src + i);
    float4 b = *(const float4*)(src + i + 4);
    u16 o8[8] = { f2bf(a.x), f2bf(a.y), f2bf(a.z), f2bf(a.w),
                  f2bf(b.x), f2bf(b.y), f2bf(b.z), f2bf(b.w) };
    *(uint4*)(dst + i) = *(const uint4*)o8;
}

// ---------------------------------------------------------------------------
// gemm256: C[M,N] = A[M,K] @ B[N,K]^T  (bf16 in, bf16 out), 256x256 tile,
// BK=64, 8 waves (2M x 4N, each 128x64 out), double-buffered swizzled LDS.
// T3+T4+T5 schedule: issue tile t+1's staging a FULL tile early, counted
// s_waitcnt vmcnt(8) at iteration entry (never 0 mid-loop), raw s_barrier
// (no __syncthreads vmcnt(0) drain), 4 MFMA phases with setprio(1).
// Requires M%256==0, N%256==0, K%64==0, grid.x = (M/256)*(N/256), %8==0.
// ---------------------------------------------------------------------------
__global__ __launch_bounds__(512, 2) void gemm256(
        const u16* __restrict__ A, const u16* __restrict__ B,
        u16* __restrict__ Cb, int M, int N, int K, int gx)
{
    __shared__ __align__(16) u16 As[2][256 * 64];
    __shared__ __align__(16) u16 Bs[2][256 * 64];

    const int tid  = threadIdx.x;
    const int wave = tid >> 6, lane = tid & 63;
    const int quad = lane >> 4, l16 = lane & 15;
    const int wmi = wave >> 2, wni = wave & 3;

    // XCD-aware swizzle (grid.x % 8 == 0 at all call sites)
    const int cpx = gridDim.x >> 3;
    const int wg  = ((int)blockIdx.x & 7) * cpx + ((int)blockIdx.x >> 3);
    const long m0 = (long)(wg / gx) * 256;
    const long n0 = (long)(wg % gx) * 256;

    f32x4 acc[8][4] = {};

    // staging: 2048 chunks of 16B per 256x64 tile; thread handles chunks
    // c=i*512+tid, i=0..3. row=c>>3, col8=(c&7)*8, source col pre-swizzled
    // so LDS[row][col ^ ((row&7)<<3)] = G[row][col] (read with same XOR).
    const u16* Ag = A + m0 * (long)K;
    const u16* Bg = B + n0 * (long)K;
    long soff[4];
    int  lbase[4];
#pragma unroll
    for (int i = 0; i < 4; i++) {
        const int c = i * 512 + tid;
        const int row = c >> 3, col8 = (c & 7) * 8;
        soff[i]  = (long)row * K + (col8 ^ ((row & 7) << 3));
        lbase[i] = (i * 512 + wave * 64) * 8;   // wave-uniform LDS base (elems)
    }

    const int T = K >> 6;

    // 8 gld_lds per wave per tile -> vmcnt granularity of 8 per tile
    auto issue = [&](int t, int slot) {
#pragma unroll
        for (int i = 0; i < 4; i++) {
            gld_lds16(Ag + soff[i] + (long)t * 64, &As[slot][lbase[i]]);
            gld_lds16(Bg + soff[i] + (long)t * 64, &Bs[slot][lbase[i]]);
        }
    };

    // prologue: both slots are free -> issue tiles 0 and 1
    issue(0, 0);
    if (T > 1) issue(1, 1);

    const int swz   = (l16 & 7) << 3;
    const int arow0 = wmi * 128 + l16;
    const int brow0 = wni * 64 + l16;

    for (int t = 0; t < T; ++t) {
        const int slot = t & 1;
        // slot^1 was freed by the barrier closing tile t-1; safe to refill.
        if (t + 1 < T) {
            if (t >= 1) issue(t + 1, slot ^ 1);
            asm volatile("s_waitcnt vmcnt(8)" ::: "memory");   // tile t landed, t+1 in flight
        } else {
            asm volatile("s_waitcnt vmcnt(0)" ::: "memory");   // last tile: drain
        }
        __builtin_amdgcn_sched_barrier(0);
        __builtin_amdgcn_s_barrier();           // all waves' tile-t loads visible
        __builtin_amdgcn_sched_barrier(0);

        // B fragments for the whole tile (held in regs across phases)
        s16x8 bfrag[4][2];
#pragma unroll
        for (int nt = 0; nt < 4; nt++)
#pragma unroll
            for (int kk = 0; kk < 2; kk++)
                bfrag[nt][kk] = *(const s16x8*)&Bs[slot][(brow0 + nt * 16) * 64
                                    + ((kk * 32 + quad * 8) ^ swz)];

#pragma unroll
        for (int p = 0; p < 4; p++) {
            s16x8 af[2][2];
#pragma unroll
            for (int mtl = 0; mtl < 2; mtl++)
#pragma unroll
                for (int kk = 0; kk < 2; kk++)
                    af[mtl][kk] = *(const s16x8*)&As[slot][(arow0 + (2 * p + mtl) * 16) * 64
                                        + ((kk * 32 + quad * 8) ^ swz)];
            __builtin_amdgcn_s_barrier();       // align waves -> MFMA cluster
            asm volatile("s_waitcnt lgkmcnt(0)" ::: "memory");
            __builtin_amdgcn_sched_barrier(0);  // rule 18: pin MFMA below wait
            __builtin_amdgcn_s_setprio(1);
#pragma unroll
            for (int mtl = 0; mtl < 2; mtl++)
#pragma unroll
                for (int nt = 0; nt < 4; nt++)
#pragma unroll
                    for (int kk = 0; kk < 2; kk++)
                        acc[2 * p + mtl][nt] = __builtin_amdgcn_mfma_f32_16x16x32_bf16(
                            af[mtl][kk], bfrag[nt][kk], acc[2 * p + mtl][nt], 0, 0, 0);
            __builtin_amdgcn_s_setprio(0);
            __builtin_amdgcn_s_barrier();       // close phase (protects slot reuse)
        }
    }

    // epilogue: C/D layout col=l16, row=quad*4+r
#pragma unroll
    for (int mt = 0; mt < 8; mt++)
#pragma unroll
        for (int nt = 0; nt < 4; nt++) {
            const long col = n0 + wni * 64 + nt * 16 + l16;
#pragma unroll
            for (int r = 0; r < 4; r++) {
                const long row = m0 + wmi * 128 + mt * 16 + quad * 4 + r;
                Cb[row * (long)N + col] = f2bf(acc[mt][nt][r]);
            }
        }
}

// ---------------------------------------------------------------------------
// GEMM:  C[M,N] = A[M,K] @ B[N,K]^T   (A,B bf16, A row stride lda)
// m97 structure: 128x128 tile, BK=32, 4 waves (2x2 of 64x64), 16x16x32 MFMA.
// ep=0: Cb[idx] = bf16(acc)        ep=1: Cf[idx] = acc + Rf[idx]   (f32)
// ---------------------------------------------------------------------------
__global__ __launch_bounds__(256) void gemm_bt(
        const u16* __restrict__ A, const u16* __restrict__ B,
        u16* __restrict__ Cb, float* __restrict__ Cf, const float* __restrict__ Rf,
        int M, int N, int K, int lda, int ep)
{
    __shared__ __align__(16) u16 As[128 * 32];
    __shared__ __align__(16) u16 Bs[128 * 32];

    const int tid  = threadIdx.x;
    const int wave = tid >> 6, lane = tid & 63;
    const int quad = lane >> 4, l16 = lane & 15;
    const long m0 = (long)blockIdx.y * 128, n0 = (long)blockIdx.x * 128;
    const int wm = (wave >> 1) * 64, wn = (wave & 1) * 64;

    f32x4 acc[4][4] = {};

    const int c0 = tid, c1 = tid + 256;
    const u16* Ag = A + m0 * (long)lda;
    const u16* Bg = B + n0 * (long)K;
    const long aA0 = (long)(c0 >> 2) * lda + (c0 & 3) * 8;
    const long aA1 = (long)(c1 >> 2) * lda + (c1 & 3) * 8;
    const long aB0 = (long)(c0 >> 2) * K + (c0 & 3) * 8;
    const long aB1 = (long)(c1 >> 2) * K + (c1 & 3) * 8;
    const int lb0 = (wave * 64) * 8;
    const int lb1 = (256 + wave * 64) * 8;

    for (int k0 = 0; k0 < K; k0 += 32) {
        __syncthreads();
        gld_lds16(Ag + aA0 + k0, &As[lb0]);
        gld_lds16(Ag + aA1 + k0, &As[lb1]);
        gld_lds16(Bg + aB0 + k0, &Bs[lb0]);
        gld_lds16(Bg + aB1 + k0, &Bs[lb1]);
        __syncthreads();

        s16x8 af[4], bfr[4];
#pragma unroll
        for (int t = 0; t < 4; t++) {
            af[t]  = *(const s16x8*)&As[(wm + t * 16 + l16) * 32 + quad * 8];
            bfr[t] = *(const s16x8*)&Bs[(wn + t * 16 + l16) * 32 + quad * 8];
        }
#pragma unroll
        for (int mt = 0; mt < 4; mt++)
#pragma unroll
            for (int nt = 0; nt < 4; nt++)
                acc[mt][nt] = __builtin_amdgcn_mfma_f32_16x16x32_bf16(
                    af[mt], bfr[nt], acc[mt][nt], 0, 0, 0);
    }

#pragma unroll
    for (int mt = 0; mt < 4; mt++)
#pragma unroll
        for (int nt = 0; nt < 4; nt++) {
            const long col = n0 + wn + nt * 16 + l16;
#pragma unroll
            for (int r = 0; r < 4; r++) {
                const long row = m0 + wm + mt * 16 + quad * 4 + r;
                const long idx = row * N + col;
                const float v = acc[mt][nt][r];
                if (ep == 0) Cb[idx] = f2bf(v);
                else         Cf[idx] = v + Rf[idx];
            }
        }
}

// ---------------------------------------------------------------------------
// Flash attention, Br=64 (16 q-rows/wave), Bc=64, head_dim=128, S=2048.
// q/k/v (bf16) layout: [B,S,NH,HD] with row stride ld. bias/mask f32.
// LDS tiles XOR-swizzled (see R1). Output O row stride 2048.
// ---------------------------------------------------------------------------
__global__ __launch_bounds__(256) void flash_attn(
        const u16* __restrict__ Q, const u16* __restrict__ Kp,
        const u16* __restrict__ V, int ld, const float* __restrict__ bias,
        const float* __restrict__ mask, u16* __restrict__ O)
{
    const int tid  = threadIdx.x;
    const int wave = tid >> 6, lane = tid & 63;
    const int quad = lane >> 4, l16 = lane & 15;
    const int q0 = blockIdx.x * 64, h = blockIdx.y, b = blockIdx.z;

    __shared__ __align__(16) u16 Ks[64 * 128];      // [k][d] row-major, swizzled
    __shared__ __align__(16) u16 Vt[128 * 64];      // [d][k] transposed, swizzled
    __shared__ __align__(16) u16 Ps[4][16 * 64];    // per-wave P, swizzled

    const long baseI = (long)b * 2048 * ld + (long)h * 128;
    const long baseO = (long)b * 2048 * 2048 + (long)h * 128;

    s16x8 qf[4];
    {
        const u16* qp = Q + baseI + (long)(q0 + wave * 16 + l16) * ld;
#pragma unroll
        for (int kk = 0; kk < 4; kk++)
            qf[kk] = *(const s16x8*)(qp + kk * 32 + quad * 8);
    }

    f32x4 oacc[8] = {};
    float m_i[4] = { -1e30f, -1e30f, -1e30f, -1e30f };
    float l_i[4] = { 0.f, 0.f, 0.f, 0.f };
    const float scale = 0.08838834764831845f;  // 1/sqrt(128)
    const int kswz = (l16 & 7) << 3;

    for (int k0 = 0; k0 < 2048; k0 += 64) {
        __syncthreads();
#pragma unroll
        for (int it = 0; it < 4; it++) {
            const int c = it * 256 + tid;
            const int row = c >> 4, col8 = (c & 15) * 8;
            const int src = col8 ^ ((row & 7) << 3);
            gld_lds16(Kp + baseI + (long)(k0 + row) * ld + src,
                      &Ks[(it * 256 + wave * 64) * 8]);
        }
#pragma unroll
        for (int it = 0; it < 4; it++) {
            const int c = it * 256 + tid;
            const int row = c >> 4, col8 = (c & 15) * 8;
            uint4 raw = *(const uint4*)(V + baseI + (long)(k0 + row) * ld + col8);
            const u16* e = (const u16*)&raw;
#pragma unroll
            for (int j = 0; j < 8; j++) {
                const int d = col8 + j;
                const int swzv = ((d & 7) ^ ((d >> 3) & 7)) << 3;
                Vt[d * 64 + (row ^ swzv)] = e[j];
            }
        }
        __syncthreads();

        float sv[4][4];
#pragma unroll
        for (int nt = 0; nt < 4; nt++) {
            f32x4 sa = { 0.f, 0.f, 0.f, 0.f };
#pragma unroll
            for (int kk = 0; kk < 4; kk++) {
                s16x8 kf = *(const s16x8*)&Ks[(nt * 16 + l16) * 128
                                              + ((kk * 32 + quad * 8) ^ kswz)];
                sa = __builtin_amdgcn_mfma_f32_16x16x32_bf16(qf[kk], kf, sa, 0, 0, 0);
            }
            const int kcol = k0 + nt * 16 + l16;
#pragma unroll
            for (int r = 0; r < 4; r++) {
                const int qrow = q0 + wave * 16 + quad * 4 + r;
                float val = sa[r] * scale;
                val += bias[((long)h * 2048 + qrow) * 2048 + kcol];
                val += mask[(long)qrow * 2048 + kcol];
                sv[nt][r] = val;
            }
        }

        float alpha[4];
#pragma unroll
        for (int r = 0; r < 4; r++) {
            float mx = fmaxf(fmaxf(sv[0][r], sv[1][r]), fmaxf(sv[2][r], sv[3][r]));
#pragma unroll
            for (int off = 1; off < 16; off <<= 1) mx = fmaxf(mx, __shfl_xor(mx, off));
            const float mnew = fmaxf(m_i[r], mx);
            alpha[r] = __expf(m_i[r] - mnew);
            m_i[r] = mnew;
            float rs = 0.f;
#pragma unroll
            for (int nt = 0; nt < 4; nt++) {
                const float pv = __expf(sv[nt][r] - mnew);
                sv[nt][r] = pv;
                rs += pv;
            }
#pragma unroll
            for (int off = 1; off < 16; off <<= 1) rs += __shfl_xor(rs, off);
            l_i[r] = l_i[r] * alpha[r] + rs;
        }

#pragma unroll
        for (int nt = 0; nt < 4; nt++)
#pragma unroll
            for (int r = 0; r < 4; r++) {
                const int prow = quad * 4 + r;
                Ps[wave][prow * 64 + ((nt * 16 + l16) ^ ((prow & 7) << 3))]
                    = f2bf(sv[nt][r]);
            }

#pragma unroll
        for (int dt = 0; dt < 8; dt++)
#pragma unroll
            for (int r = 0; r < 4; r++)
                oacc[dt][r] *= alpha[r];

#pragma unroll
        for (int kk2 = 0; kk2 < 2; kk2++) {
            s16x8 pf = *(const s16x8*)&Ps[wave][l16 * 64
                                               + ((kk2 * 32 + quad * 8) ^ kswz)];
#pragma unroll
            for (int dt = 0; dt < 8; dt++) {
                const int d = dt * 16 + l16;
                const int vswz = ((d & 7) ^ ((d >> 3) & 7)) << 3;
                s16x8 vf = *(const s16x8*)&Vt[d * 64
                                              + ((kk2 * 32 + quad * 8) ^ vswz)];
                oacc[dt] = __builtin_amdgcn_mfma_f32_16x16x32_bf16(pf, vf, oacc[dt], 0, 0, 0);
            }
        }
    }

#pragma unroll
    for (int dt = 0; dt < 8; dt++)
#pragma unroll
        for (int r = 0; r < 4; r++) {
            const int qrow = q0 + wave * 16 + quad * 4 + r;
            O[baseO + (long)qrow * 2048 + dt * 16 + l16] = f2bf(oacc[dt][r] / l_i[r]);
        }
}

// ---------------------------------------------------------------------------
// RMSNorm: f32 in (row of 2048), f32 weight, bf16 out. One block per row.
// ---------------------------------------------------------------------------
__global__ __launch_bounds__(256) void rmsnorm_f32(
        const float* __restrict__ x, const float* __restrict__ w,
        u16* __restrict__ out)
{
    const int row = blockIdx.x, tid = threadIdx.x;
    const float* xr = x + (long)row * 2048;
    float4 f0 = *(const float4*)(xr + tid * 8);
    float4 f1 = *(const float4*)(xr + tid * 8 + 4);
    float v[8] = { f0.x, f0.y, f0.z, f0.w, f1.x, f1.y, f1.z, f1.w };
    float ss = 0.f;
#pragma unroll
    for (int j = 0; j < 8; j++) ss += v[j] * v[j];
#pragma unroll
    for (int off = 32; off > 0; off >>= 1) ss += __shfl_xor(ss, off);
    __shared__ float red[4];
    if ((tid & 63) == 0) red[tid >> 6] = ss;
    __syncthreads();
    const float tot = red[0] + red[1] + red[2] + red[3];
    const float sc = rsqrtf(tot * (1.0f / 2048.0f) + 1e-5f);
    float4 w0 = *(const float4*)(w + tid * 8);
    float4 w1v = *(const float4*)(w + tid * 8 + 4);
    const float wv[8] = { w0.x, w0.y, w0.z, w0.w, w1v.x, w1v.y, w1v.z, w1v.w };
    u16 o8[8];
#pragma unroll
    for (int j = 0; j < 8; j++) o8[j] = f2bf(v[j] * sc * wv[j]);
    *(uint4*)(out + (long)row * 2048 + tid * 8) = *(const uint4*)o8;
}

// ---------------------------------------------------------------------------
// g = silu(a)*b on the fused [4096, 11264] buffer: a = cols 0..5631,
// b = cols 5632..11263, g written in place over a. One block per row.
// ---------------------------------------------------------------------------
__global__ __launch_bounds__(704) void silu_mul_rows(u16* __restrict__ s13)
{
    const long rb = (long)blockIdx.x * 11264;
    const int col8 = threadIdx.x * 8;
    uint4 ra = *(const uint4*)(s13 + rb + col8);
    uint4 rbv = *(const uint4*)(s13 + rb + 5632 + col8);
    const u16* ea = (const u16*)&ra;
    const u16* eb = (const u16*)&rbv;
    u16 o8[8];
#pragma unroll
    for (int j = 0; j < 8; j++) {
        const float fa = bf2f(ea[j]);
        const float fb = bf2f(eb[j]);
        const float s = fa / (1.f + __expf(-fa));
        o8[j] = f2bf(s * fb);
    }
    *(uint4*)(s13 + rb + col8) = *(const uint4*)o8;
}

// ---------------------------------------------------------------------------
extern "C" void kernel_launch(void* const* d_in, const int* in_sizes, int n_in,
                              void* d_out, int out_size, void* d_ws, size_t ws_size,
                              hipStream_t stream)
{
    const float* x    = (const float*)d_in[0];
    const float* mask = (const float*)d_in[1];
    const float* bias = (const float*)d_in[2];
    const float* wq   = (const float*)d_in[3];
    const float* wk   = (const float*)d_in[4];
    const float* wv   = (const float*)d_in[5];
    const float* wo   = (const float*)d_in[6];
    const float* w1   = (const float*)d_in[7];
    const float* w2   = (const float*)d_in[8];
    const float* w3   = (const float*)d_in[9];
    const float* anw  = (const float*)d_in[10];
    const float* fnw  = (const float*)d_in[11];
    float* out = (float*)d_out;       // also doubles as h1 (f32 residual buffer)

    const long SZA = 2048L * 2048;    // attention weight elems
    const long SZF = 5632L * 2048;    // FFN weight elems

    char* p = (char*)d_ws;
    // wq,wk,wv contiguous -> fused [6144,2048] B; w1,w3 contiguous -> [11264,2048]
    u16* wqb = (u16*)p;  u16* wkb = wqb + SZA;  u16* wvb = wkb + SZA;
    u16* wob = wvb + SZA;
    u16* w1b = wob + SZA;  u16* w3b = w1b + SZF;  u16* w2b = w3b + SZF;
    p += (4 * SZA + 3 * SZF) * 2;
    const size_t SZ = (size_t)4096 * 2048 * 2;           // 16 MiB bf16 activation
    u16* h_buf  = (u16*)p;  p += SZ;                     // h, attn_out, f
    u16* qkv    = (u16*)p;  p += (size_t)4096 * 6144 * 2;   // fused q|k|v
    u16* s13    = (u16*)p;  p += (size_t)4096 * 11264 * 2;  // fused w1|w3 out, g
    // total ws used ~238 MB

    // weights f32 -> bf16
    cvt_f32_bf16<<<2048, 256, 0, stream>>>(wq, wqb, SZA);
    cvt_f32_bf16<<<2048, 256, 0, stream>>>(wk, wkb, SZA);
    cvt_f32_bf16<<<2048, 256, 0, stream>>>(wv, wvb, SZA);
    cvt_f32_bf16<<<2048, 256, 0, stream>>>(wo, wob, SZA);
    cvt_f32_bf16<<<5632, 256, 0, stream>>>(w1, w1b, SZF);
    cvt_f32_bf16<<<5632, 256, 0, stream>>>(w3, w3b, SZF);
    cvt_f32_bf16<<<5632, 256, 0, stream>>>(w2, w2b, SZF);

    rmsnorm_f32<<<4096, 256, 0, stream>>>(x, anw, h_buf);
    // fused QKV: [4096,6144] = h @ [wq;wk;wv]^T   grid 24*16=384 (%8==0)
    gemm256<<<384, 512, 0, stream>>>(h_buf, wqb, qkv, 4096, 6144, 2048, 24);
    flash_attn<<<dim3(32, 16, 2), 256, 0, stream>>>(qkv, qkv + 2048, qkv + 4096,
                                                    6144, bias, mask, h_buf);
    // h1 = x + attn_out @ wo^T   (f32, stored in d_out)
    gemm_bt<<<dim3(16, 32), 256, 0, stream>>>(h_buf, wob, nullptr, out, x,
                                              4096, 2048, 2048, 2048, 1);
    rmsnorm_f32<<<4096, 256, 0, stream>>>(out, fnw, h_buf);
    // fused FFN up: [4096,11264] = f @ [w1;w3]^T  grid 44*16=704 (%8==0)
    gemm256<<<704, 512, 0, stream>>>(h_buf, w1b, s13, 4096, 11264, 2048, 44);
    silu_mul_rows<<<4096, 704, 0, stream>>>(s13);
    // out = h1 + g @ w2^T   (g = s13 cols 0..5631, row stride 11264)
    gemm_bt<<<dim3(16, 32), 256, 0, stream>>>(s13, w2b, nullptr, out, out,
                                              4096, 2048, 5632, 11264, 1);
}

// Round 4
// 1414.427 us; speedup vs baseline: 1.0498x; 1.0161x over previous
//
#include <hip/hip_runtime.h>
#include <stdint.h>

typedef uint16_t u16;
typedef __attribute__((ext_vector_type(8))) short s16x8;
typedef __attribute__((ext_vector_type(4))) float f32x4;

typedef const __attribute__((address_space(1))) void* gptr_t;
typedef __attribute__((address_space(3))) void* lptr_t;

__device__ __forceinline__ float bf2f(u16 u) { return __uint_as_float(((unsigned)u) << 16); }
__device__ __forceinline__ u16 f2bf(float f) {
    unsigned u = __float_as_uint(f);
    u += 0x7fffu + ((u >> 16) & 1u);   // RNE (finite values only in this net)
    return (u16)(u >> 16);
}
__device__ __forceinline__ void gld_lds16(const void* g, void* l) {
    __builtin_amdgcn_global_load_lds((gptr_t)g, (lptr_t)l, 16, 0, 0);
}

// ---------------------------------------------------------------------------
// f32 -> bf16 conversion, 8 elems/thread, n % 2048 == 0
// ---------------------------------------------------------------------------
__global__ __launch_bounds__(256) void cvt_f32_bf16(const float* __restrict__ src,
                                                    u16* __restrict__ dst, long n)
{
    const long i = ((long)blockIdx.x * 256 + threadIdx.x) * 8;
    if (i >= n) return;
    float4 a = *(const float4*)(src + i);
    float4 b = *(const float4*)(src + i + 4);
    u16 o8[8] = { f2bf(a.x), f2bf(a.y), f2bf(a.z), f2bf(a.w),
                  f2bf(b.x), f2bf(b.y), f2bf(b.z), f2bf(b.w) };
    *(uint4*)(dst + i) = *(const uint4*)o8;
}

// ---------------------------------------------------------------------------
// gemm256t<BN,EP>: C[M,N] = A[M,K] @ B[N,K]^T  (bf16 in), 256xBN tile, BK=64,
// 8 waves (2M x 4N; wave owns 128 x BN/4), double-buffered swizzled LDS.
// T3+T4+T5 schedule: issue tile t+1's staging a FULL tile early, counted
// s_waitcnt vmcnt(loads/tile) at iteration entry (never 0 mid-loop), raw
// s_barrier, 4 MFMA phases with setprio(1).
// EP=0: Cb = bf16(acc)   EP=1: Cf = acc + Rf (f32)
// Requires M%256==0, N%BN==0, K%64==0, grid.x=(M/256)*(N/BN) with %8==0,
// gx = N/BN. A row stride = lda.
// ---------------------------------------------------------------------------
template<int BN, int EP>
__global__ __launch_bounds__(512, 2) void gemm256t(
        const u16* __restrict__ A, const u16* __restrict__ B,
        u16* __restrict__ Cb, float* __restrict__ Cf, const float* __restrict__ Rf,
        int M, int N, int K, int lda, int gx)
{
    constexpr int NB = BN / 64;   // B staging chunks per thread (2 or 4)
    constexpr int NT = BN / 64;   // 16-col strips per wave (2 or 4)
    __shared__ __align__(16) u16 As[2][256 * 64];
    __shared__ __align__(16) u16 Bs[2][BN * 64];

    const int tid  = threadIdx.x;
    const int wave = tid >> 6, lane = tid & 63;
    const int quad = lane >> 4, l16 = lane & 15;
    const int wmi = wave >> 2, wni = wave & 3;

    // XCD-aware swizzle (grid.x % 8 == 0 at all call sites)
    const int cpx = gridDim.x >> 3;
    const int wg  = ((int)blockIdx.x & 7) * cpx + ((int)blockIdx.x >> 3);
    const long m0 = (long)(wg / gx) * 256;
    const long n0 = (long)(wg % gx) * BN;

    f32x4 acc[8][NT] = {};

    // staging: 16B chunks; chunk c -> row c>>3, col8=(c&7)*8, source col
    // pre-swizzled so LDS[row][col ^ ((row&7)<<3)] = G[row][col].
    const u16* Ag = A + m0 * (long)lda;
    const u16* Bg = B + n0 * (long)K;
    long soffA[4]; int lbA[4];
#pragma unroll
    for (int i = 0; i < 4; i++) {
        const int c = i * 512 + tid;
        const int row = c >> 3, col8 = (c & 7) * 8;
        soffA[i] = (long)row * lda + (col8 ^ ((row & 7) << 3));
        lbA[i]   = (i * 512 + wave * 64) * 8;   // wave-uniform base (elems)
    }
    long soffB[NB]; int lbB[NB];
#pragma unroll
    for (int i = 0; i < NB; i++) {
        const int c = i * 512 + tid;
        const int row = c >> 3, col8 = (c & 7) * 8;
        soffB[i] = (long)row * K + (col8 ^ ((row & 7) << 3));
        lbB[i]   = (i * 512 + wave * 64) * 8;
    }

    const int T = K >> 6;

    // 4+NB gld_lds per wave per tile -> vmcnt granularity per tile
    auto issue = [&](int t, int slot) {
#pragma unroll
        for (int i = 0; i < 4; i++)
            gld_lds16(Ag + soffA[i] + (long)t * 64, &As[slot][lbA[i]]);
#pragma unroll
        for (int i = 0; i < NB; i++)
            gld_lds16(Bg + soffB[i] + (long)t * 64, &Bs[slot][lbB[i]]);
    };

    // prologue: both slots free -> issue tiles 0 and 1
    issue(0, 0);
    if (T > 1) issue(1, 1);

    const int swz   = (l16 & 7) << 3;
    const int arow0 = wmi * 128 + l16;
    const int brow0 = wni * (BN / 4) + l16;

    for (int t = 0; t < T; ++t) {
        const int slot = t & 1;
        // slot^1 was freed by the barrier closing tile t-1; safe to refill.
        if (t + 1 < T) {
            if (t >= 1) issue(t + 1, slot ^ 1);
            if constexpr (BN == 256)
                asm volatile("s_waitcnt vmcnt(8)" ::: "memory");  // tile t landed
            else
                asm volatile("s_waitcnt vmcnt(6)" ::: "memory");
        } else {
            asm volatile("s_waitcnt vmcnt(0)" ::: "memory");      // last: drain
        }
        __builtin_amdgcn_sched_barrier(0);
        __builtin_amdgcn_s_barrier();           // all waves' tile-t loads visible
        __builtin_amdgcn_sched_barrier(0);

        // B fragments for the whole tile (held in regs across phases)
        s16x8 bfrag[NT][2];
#pragma unroll
        for (int nt = 0; nt < NT; nt++)
#pragma unroll
            for (int kk = 0; kk < 2; kk++)
                bfrag[nt][kk] = *(const s16x8*)&Bs[slot][(brow0 + nt * 16) * 64
                                    + ((kk * 32 + quad * 8) ^ swz)];

#pragma unroll
        for (int p = 0; p < 4; p++) {
            s16x8 af[2][2];
#pragma unroll
            for (int mtl = 0; mtl < 2; mtl++)
#pragma unroll
                for (int kk = 0; kk < 2; kk++)
                    af[mtl][kk] = *(const s16x8*)&As[slot][(arow0 + (2 * p + mtl) * 16) * 64
                                        + ((kk * 32 + quad * 8) ^ swz)];
            __builtin_amdgcn_s_barrier();       // align waves -> MFMA cluster
            asm volatile("s_waitcnt lgkmcnt(0)" ::: "memory");
            __builtin_amdgcn_sched_barrier(0);  // rule 18: pin MFMA below wait
            __builtin_amdgcn_s_setprio(1);
#pragma unroll
            for (int mtl = 0; mtl < 2; mtl++)
#pragma unroll
                for (int nt = 0; nt < NT; nt++)
#pragma unroll
                    for (int kk = 0; kk < 2; kk++)
                        acc[2 * p + mtl][nt] = __builtin_amdgcn_mfma_f32_16x16x32_bf16(
                            af[mtl][kk], bfrag[nt][kk], acc[2 * p + mtl][nt], 0, 0, 0);
            __builtin_amdgcn_s_setprio(0);
            __builtin_amdgcn_s_barrier();       // close phase (protects slot reuse)
        }
    }

    // epilogue: C/D layout col=l16, row=quad*4+r
#pragma unroll
    for (int mt = 0; mt < 8; mt++)
#pragma unroll
        for (int nt = 0; nt < NT; nt++) {
            const long col = n0 + wni * (BN / 4) + nt * 16 + l16;
#pragma unroll
            for (int r = 0; r < 4; r++) {
                const long row = m0 + wmi * 128 + mt * 16 + quad * 4 + r;
                const long idx = row * (long)N + col;
                const float v = acc[mt][nt][r];
                if constexpr (EP == 0) Cb[idx] = f2bf(v);
                else                   Cf[idx] = v + Rf[idx];
            }
        }
}

// ---------------------------------------------------------------------------
// Flash attention, Br=64 (16 q-rows/wave), Bc=64, head_dim=128, S=2048.
// q/k/v (bf16) layout: [B,S,NH,HD] with row stride ld. bias/mask f32.
// LDS tiles XOR-swizzled (see R1). Output O row stride 2048.
// ---------------------------------------------------------------------------
__global__ __launch_bounds__(256) void flash_attn(
        const u16* __restrict__ Q, const u16* __restrict__ Kp,
        const u16* __restrict__ V, int ld, const float* __restrict__ bias,
        const float* __restrict__ mask, u16* __restrict__ O)
{
    const int tid  = threadIdx.x;
    const int wave = tid >> 6, lane = tid & 63;
    const int quad = lane >> 4, l16 = lane & 15;
    const int q0 = blockIdx.x * 64, h = blockIdx.y, b = blockIdx.z;

    __shared__ __align__(16) u16 Ks[64 * 128];      // [k][d] row-major, swizzled
    __shared__ __align__(16) u16 Vt[128 * 64];      // [d][k] transposed, swizzled
    __shared__ __align__(16) u16 Ps[4][16 * 64];    // per-wave P, swizzled

    const long baseI = (long)b * 2048 * ld + (long)h * 128;
    const long baseO = (long)b * 2048 * 2048 + (long)h * 128;

    s16x8 qf[4];
    {
        const u16* qp = Q + baseI + (long)(q0 + wave * 16 + l16) * ld;
#pragma unroll
        for (int kk = 0; kk < 4; kk++)
            qf[kk] = *(const s16x8*)(qp + kk * 32 + quad * 8);
    }

    f32x4 oacc[8] = {};
    float m_i[4] = { -1e30f, -1e30f, -1e30f, -1e30f };
    float l_i[4] = { 0.f, 0.f, 0.f, 0.f };
    const float scale = 0.08838834764831845f;  // 1/sqrt(128)
    const int kswz = (l16 & 7) << 3;

    for (int k0 = 0; k0 < 2048; k0 += 64) {
        __syncthreads();
#pragma unroll
        for (int it = 0; it < 4; it++) {
            const int c = it * 256 + tid;
            const int row = c >> 4, col8 = (c & 15) * 8;
            const int src = col8 ^ ((row & 7) << 3);
            gld_lds16(Kp + baseI + (long)(k0 + row) * ld + src,
                      &Ks[(it * 256 + wave * 64) * 8]);
        }
#pragma unroll
        for (int it = 0; it < 4; it++) {
            const int c = it * 256 + tid;
            const int row = c >> 4, col8 = (c & 15) * 8;
            uint4 raw = *(const uint4*)(V + baseI + (long)(k0 + row) * ld + col8);
            const u16* e = (const u16*)&raw;
#pragma unroll
            for (int j = 0; j < 8; j++) {
                const int d = col8 + j;
                const int swzv = ((d & 7) ^ ((d >> 3) & 7)) << 3;
                Vt[d * 64 + (row ^ swzv)] = e[j];
            }
        }
        __syncthreads();

        float sv[4][4];
#pragma unroll
        for (int nt = 0; nt < 4; nt++) {
            f32x4 sa = { 0.f, 0.f, 0.f, 0.f };
#pragma unroll
            for (int kk = 0; kk < 4; kk++) {
                s16x8 kf = *(const s16x8*)&Ks[(nt * 16 + l16) * 128
                                              + ((kk * 32 + quad * 8) ^ kswz)];
                sa = __builtin_amdgcn_mfma_f32_16x16x32_bf16(qf[kk], kf, sa, 0, 0, 0);
            }
            const int kcol = k0 + nt * 16 + l16;
#pragma unroll
            for (int r = 0; r < 4; r++) {
                const int qrow = q0 + wave * 16 + quad * 4 + r;
                float val = sa[r] * scale;
                val += bias[((long)h * 2048 + qrow) * 2048 + kcol];
                val += mask[(long)qrow * 2048 + kcol];
                sv[nt][r] = val;
            }
        }

        float alpha[4];
#pragma unroll
        for (int r = 0; r < 4; r++) {
            float mx = fmaxf(fmaxf(sv[0][r], sv[1][r]), fmaxf(sv[2][r], sv[3][r]));
#pragma unroll
            for (int off = 1; off < 16; off <<= 1) mx = fmaxf(mx, __shfl_xor(mx, off));
            const float mnew = fmaxf(m_i[r], mx);
            alpha[r] = __expf(m_i[r] - mnew);
            m_i[r] = mnew;
            float rs = 0.f;
#pragma unroll
            for (int nt = 0; nt < 4; nt++) {
                const float pv = __expf(sv[nt][r] - mnew);
                sv[nt][r] = pv;
                rs += pv;
            }
#pragma unroll
            for (int off = 1; off < 16; off <<= 1) rs += __shfl_xor(rs, off);
            l_i[r] = l_i[r] * alpha[r] + rs;
        }

#pragma unroll
        for (int nt = 0; nt < 4; nt++)
#pragma unroll
            for (int r = 0; r < 4; r++) {
                const int prow = quad * 4 + r;
                Ps[wave][prow * 64 + ((nt * 16 + l16) ^ ((prow & 7) << 3))]
                    = f2bf(sv[nt][r]);
            }

#pragma unroll
        for (int dt = 0; dt < 8; dt++)
#pragma unroll
            for (int r = 0; r < 4; r++)
                oacc[dt][r] *= alpha[r];

#pragma unroll
        for (int kk2 = 0; kk2 < 2; kk2++) {
            s16x8 pf = *(const s16x8*)&Ps[wave][l16 * 64
                                               + ((kk2 * 32 + quad * 8) ^ kswz)];
#pragma unroll
            for (int dt = 0; dt < 8; dt++) {
                const int d = dt * 16 + l16;
                const int vswz = ((d & 7) ^ ((d >> 3) & 7)) << 3;
                s16x8 vf = *(const s16x8*)&Vt[d * 64
                                              + ((kk2 * 32 + quad * 8) ^ vswz)];
                oacc[dt] = __builtin_amdgcn_mfma_f32_16x16x32_bf16(pf, vf, oacc[dt], 0, 0, 0);
            }
        }
    }

#pragma unroll
    for (int dt = 0; dt < 8; dt++)
#pragma unroll
        for (int r = 0; r < 4; r++) {
            const int qrow = q0 + wave * 16 + quad * 4 + r;
            O[baseO + (long)qrow * 2048 + dt * 16 + l16] = f2bf(oacc[dt][r] / l_i[r]);
        }
}

// ---------------------------------------------------------------------------
// RMSNorm: f32 in (row of 2048), f32 weight, bf16 out. One block per row.
// ---------------------------------------------------------------------------
__global__ __launch_bounds__(256) void rmsnorm_f32(
        const float* __restrict__ x, const float* __restrict__ w,
        u16* __restrict__ out)
{
    const int row = blockIdx.x, tid = threadIdx.x;
    const float* xr = x + (long)row * 2048;
    float4 f0 = *(const float4*)(xr + tid * 8);
    float4 f1 = *(const float4*)(xr + tid * 8 + 4);
    float v[8] = { f0.x, f0.y, f0.z, f0.w, f1.x, f1.y, f1.z, f1.w };
    float ss = 0.f;
#pragma unroll
    for (int j = 0; j < 8; j++) ss += v[j] * v[j];
#pragma unroll
    for (int off = 32; off > 0; off >>= 1) ss += __shfl_xor(ss, off);
    __shared__ float red[4];
    if ((tid & 63) == 0) red[tid >> 6] = ss;
    __syncthreads();
    const float tot = red[0] + red[1] + red[2] + red[3];
    const float sc = rsqrtf(tot * (1.0f / 2048.0f) + 1e-5f);
    float4 w0 = *(const float4*)(w + tid * 8);
    float4 w1v = *(const float4*)(w + tid * 8 + 4);
    const float wv[8] = { w0.x, w0.y, w0.z, w0.w, w1v.x, w1v.y, w1v.z, w1v.w };
    u16 o8[8];
#pragma unroll
    for (int j = 0; j < 8; j++) o8[j] = f2bf(v[j] * sc * wv[j]);
    *(uint4*)(out + (long)row * 2048 + tid * 8) = *(const uint4*)o8;
}

// ---------------------------------------------------------------------------
// g = silu(a)*b on the fused [4096, 11264] buffer: a = cols 0..5631,
// b = cols 5632..11263, g written in place over a. One block per row.
// ---------------------------------------------------------------------------
__global__ __launch_bounds__(704) void silu_mul_rows(u16* __restrict__ s13)
{
    const long rb = (long)blockIdx.x * 11264;
    const int col8 = threadIdx.x * 8;
    uint4 ra = *(const uint4*)(s13 + rb + col8);
    uint4 rbv = *(const uint4*)(s13 + rb + 5632 + col8);
    const u16* ea = (const u16*)&ra;
    const u16* eb = (const u16*)&rbv;
    u16 o8[8];
#pragma unroll
    for (int j = 0; j < 8; j++) {
        const float fa = bf2f(ea[j]);
        const float fb = bf2f(eb[j]);
        const float s = fa / (1.f + __expf(-fa));
        o8[j] = f2bf(s * fb);
    }
    *(uint4*)(s13 + rb + col8) = *(const uint4*)o8;
}

// ---------------------------------------------------------------------------
extern "C" void kernel_launch(void* const* d_in, const int* in_sizes, int n_in,
                              void* d_out, int out_size, void* d_ws, size_t ws_size,
                              hipStream_t stream)
{
    const float* x    = (const float*)d_in[0];
    const float* mask = (const float*)d_in[1];
    const float* bias = (const float*)d_in[2];
    const float* wq   = (const float*)d_in[3];
    const float* wk   = (const float*)d_in[4];
    const float* wv   = (const float*)d_in[5];
    const float* wo   = (const float*)d_in[6];
    const float* w1   = (const float*)d_in[7];
    const float* w2   = (const float*)d_in[8];
    const float* w3   = (const float*)d_in[9];
    const float* anw  = (const float*)d_in[10];
    const float* fnw  = (const float*)d_in[11];
    float* out = (float*)d_out;       // also doubles as h1 (f32 residual buffer)

    const long SZA = 2048L * 2048;    // attention weight elems
    const long SZF = 5632L * 2048;    // FFN weight elems

    char* p = (char*)d_ws;
    // wq,wk,wv contiguous -> fused [6144,2048] B; w1,w3 contiguous -> [11264,2048]
    u16* wqb = (u16*)p;  u16* wkb = wqb + SZA;  u16* wvb = wkb + SZA;
    u16* wob = wvb + SZA;
    u16* w1b = wob + SZA;  u16* w3b = w1b + SZF;  u16* w2b = w3b + SZF;
    p += (4 * SZA + 3 * SZF) * 2;
    const size_t SZ = (size_t)4096 * 2048 * 2;           // 16 MiB bf16 activation
    u16* h_buf  = (u16*)p;  p += SZ;                     // h, attn_out, f
    u16* qkv    = (u16*)p;  p += (size_t)4096 * 6144 * 2;   // fused q|k|v
    u16* s13    = (u16*)p;  p += (size_t)4096 * 11264 * 2;  // fused w1|w3 out, g
    // total ws used ~238 MB

    // weights f32 -> bf16
    cvt_f32_bf16<<<2048, 256, 0, stream>>>(wq, wqb, SZA);
    cvt_f32_bf16<<<2048, 256, 0, stream>>>(wk, wkb, SZA);
    cvt_f32_bf16<<<2048, 256, 0, stream>>>(wv, wvb, SZA);
    cvt_f32_bf16<<<2048, 256, 0, stream>>>(wo, wob, SZA);
    cvt_f32_bf16<<<5632, 256, 0, stream>>>(w1, w1b, SZF);
    cvt_f32_bf16<<<5632, 256, 0, stream>>>(w3, w3b, SZF);
    cvt_f32_bf16<<<5632, 256, 0, stream>>>(w2, w2b, SZF);

    rmsnorm_f32<<<4096, 256, 0, stream>>>(x, anw, h_buf);
    // fused QKV: [4096,6144] = h @ [wq;wk;wv]^T  grid 16*48=768 = 3 exact rounds
    gemm256t<128, 0><<<768, 512, 0, stream>>>(h_buf, wqb, qkv, nullptr, nullptr,
                                              4096, 6144, 2048, 2048, 48);
    flash_attn<<<dim3(32, 16, 2), 256, 0, stream>>>(qkv, qkv + 2048, qkv + 4096,
                                                    6144, bias, mask, h_buf);
    // h1 = x + attn_out @ wo^T  (f32 into d_out)  grid 16*16=256 = 1 exact round
    gemm256t<128, 1><<<256, 512, 0, stream>>>(h_buf, wob, nullptr, out, x,
                                              4096, 2048, 2048, 2048, 16);
    rmsnorm_f32<<<4096, 256, 0, stream>>>(out, fnw, h_buf);
    // fused FFN up: [4096,11264] = f @ [w1;w3]^T  grid 16*44=704
    gemm256t<256, 0><<<704, 512, 0, stream>>>(h_buf, w1b, s13, nullptr, nullptr,
                                              4096, 11264, 2048, 2048, 44);
    silu_mul_rows<<<4096, 704, 0, stream>>>(s13);
    // out = h1 + g @ w2^T  (g = s13 cols 0..5631, lda 11264)  grid 256
    gemm256t<128, 1><<<256, 512, 0, stream>>>(s13, w2b, nullptr, out, out,
                                              4096, 2048, 5632, 11264, 16);
}